// Round 7
// baseline (236.542 us; speedup 1.0000x reference)
//
#include <hip/hip_runtime.h>

// GCN layer: out = Ahat @ x @ W^T + bias, Ahat = D^-1/2 (A + I) D^-1/2
// Pipeline: global-atomic degree count -> fixed-capacity bucket binning
// (dst>>8, LDS counting sort, contiguous run writes) -> y' = dinv*(x@W^T)
// via bf16 MFMA -> FUSED per-bucket kernel: LDS counting-sort by dst&255
// (stays in LDS) + per-dest gather + epilogue. No dest-sorted global CSR.

#define NBMAX 400
#define CAP   5120   // bucket capacity: mean 4096 + 16 sigma (sigma ~ 64)

typedef short bf16x8 __attribute__((ext_vector_type(8)));
typedef float f32x4  __attribute__((ext_vector_type(4)));

__device__ inline float bflo(unsigned u) { return __uint_as_float(u << 16); }
__device__ inline float bfhi(unsigned u) { return __uint_as_float(u & 0xFFFF0000u); }
__device__ inline unsigned short f2bf(float f) {           // round-nearest-even
    unsigned u = __float_as_uint(f);
    u += 0x7FFFu + ((u >> 16) & 1u);
    return (unsigned short)(u >> 16);
}

// Degree count via global atomics (cnt is 400 KB, L2-resident).
// Block 0 also initializes the bucket cursors (replaces k_initcur).
__global__ __launch_bounds__(256) void k_deg(const int* __restrict__ col,
                                             int* __restrict__ cnt,
                                             int* __restrict__ gcur, int E, int NB) {
    if (blockIdx.x == 0)
        for (int b = threadIdx.x; b < NB; b += 256) gcur[b] = b * CAP;
    int i4 = (blockIdx.x * 256 + threadIdx.x) * 4;
    if (i4 + 3 < E) {
        int4 c = *(const int4*)(col + i4);
        atomicAdd(&cnt[c.x], 1); atomicAdd(&cnt[c.y], 1);
        atomicAdd(&cnt[c.z], 1); atomicAdd(&cnt[c.w], 1);
    } else {
        int lim = min(i4 + 4, E);
        for (int j = i4; j < lim; ++j) atomicAdd(&cnt[col[j]], 1);
    }
}

// Chunk-local LDS counting sort by bucket (dst>>8); contiguous run copy-out of
// packed (src | (dst&255)<<24) records into fixed-stride bucket regions.
__global__ __launch_bounds__(256) void k_bin(const int* __restrict__ row,
                                             const int* __restrict__ col,
                                             int* __restrict__ gcur,
                                             unsigned int* __restrict__ ebuf, int E) {
    __shared__ unsigned int   sorted4[4096];   // 16 KB packed records
    __shared__ unsigned short sbkt[4096];      //  8 KB bucket id per slot
    __shared__ int h[NBMAX], hstart[NBMAX], hcur[NBMAX], gof[NBMAX];
    int t = threadIdx.x;
    int base = blockIdx.x * 4096;
    int total = min(4096, E - base);

    int rr[16], cc[16];
    #pragma unroll
    for (int i = 0; i < 4; ++i) {
        int e0 = (t + i * 256) * 4;
        if (e0 + 3 < total) {
            int4 r4 = *(const int4*)(row + base + e0);
            int4 c4 = *(const int4*)(col + base + e0);
            rr[i*4+0]=r4.x; rr[i*4+1]=r4.y; rr[i*4+2]=r4.z; rr[i*4+3]=r4.w;
            cc[i*4+0]=c4.x; cc[i*4+1]=c4.y; cc[i*4+2]=c4.z; cc[i*4+3]=c4.w;
        } else {
            #pragma unroll
            for (int j = 0; j < 4; ++j) {
                int e = e0 + j;
                if (e < total) { rr[i*4+j] = row[base+e]; cc[i*4+j] = col[base+e]; }
                else cc[i*4+j] = -1;
            }
        }
    }
    for (int b = t; b < NBMAX; b += 256) h[b] = 0;
    __syncthreads();
    #pragma unroll
    for (int i = 0; i < 16; ++i)
        if (cc[i] >= 0) atomicAdd(&h[cc[i] >> 8], 1);
    __syncthreads();
    if (t < 64) {                              // wave-0 scan of h
        int lo = t * 7;
        int loc[7]; int s = 0;
        #pragma unroll
        for (int i = 0; i < 7; ++i) {
            loc[i] = s;
            int idx = lo + i;
            s += (idx < NBMAX) ? h[idx] : 0;
        }
        int incl = s;
        for (int off = 1; off < 64; off <<= 1) {
            int v = __shfl_up(incl, off);
            if (t >= off) incl += v;
        }
        int ex = incl - s;
        #pragma unroll
        for (int i = 0; i < 7; ++i) {
            int idx = lo + i;
            if (idx < NBMAX) hstart[idx] = ex + loc[i];
        }
    }
    __syncthreads();
    for (int b = t; b < NBMAX; b += 256) hcur[b] = hstart[b];
    __syncthreads();
    #pragma unroll
    for (int i = 0; i < 16; ++i) {
        if (cc[i] >= 0) {
            int b = cc[i] >> 8;
            int rank = atomicAdd(&hcur[b], 1);
            sorted4[rank] = (unsigned)rr[i] | ((unsigned)(cc[i] & 255) << 24);
            sbkt[rank] = (unsigned short)b;
        }
    }
    for (int b = t; b < NBMAX; b += 256) {
        int m = h[b];
        gof[b] = m ? atomicAdd(&gcur[b], m) : 0;
    }
    __syncthreads();
    for (int i = t; i < total; i += 256) {     // contiguous per-bucket runs
        int b = sbkt[i];
        ebuf[gof[b] + (i - hstart[b])] = sorted4[i];
    }
}

// y' = rsqrt(deg+1) * (x @ W^T) via bf16 MFMA 16x16x32; 64 rows per block.
// LDS rows padded to 72 bf16 (144 B -> 2-way max bank aliasing).
__global__ __launch_bounds__(256) void k_gemm(const float* __restrict__ x,
                                              const float* __restrict__ W,
                                              const int* __restrict__ cnt,
                                              unsigned short* __restrict__ yb, int n) {
    __shared__ __align__(16) unsigned short xs[64][72];
    __shared__ __align__(16) unsigned short Wb[64][72];
    int t = threadIdx.x;
    long long total = (long long)n * 64;
    long long xbase = (long long)blockIdx.x * 4096;
    #pragma unroll
    for (int i = 0; i < 4; ++i) {
        int idx = t + i * 256;                 // float4 index 0..1023
        int r = idx >> 4, c4 = (idx & 15) << 2;
        long long g = xbase + (long long)idx * 4;
        float4 v;
        if (g + 3 < total) v = *(const float4*)(x + g);
        else {
            v.x = (g + 0 < total) ? x[g + 0] : 0.f;
            v.y = (g + 1 < total) ? x[g + 1] : 0.f;
            v.z = (g + 2 < total) ? x[g + 2] : 0.f;
            v.w = (g + 3 < total) ? x[g + 3] : 0.f;
        }
        ushort4 o; o.x = f2bf(v.x); o.y = f2bf(v.y); o.z = f2bf(v.z); o.w = f2bf(v.w);
        *(ushort4*)&xs[r][c4] = o;
        float4 wv = *(const float4*)(W + idx * 4);     // W: 4096 floats
        ushort4 wo; wo.x = f2bf(wv.x); wo.y = f2bf(wv.y); wo.z = f2bf(wv.z); wo.w = f2bf(wv.w);
        *(ushort4*)&Wb[r][c4] = wo;
    }
    __syncthreads();
    int lane = t & 63, wid = t >> 6;
    int m  = wid * 16 + (lane & 15);
    int kg = (lane >> 4) * 8;
    bf16x8 a0 = *(bf16x8*)&xs[m][kg];
    bf16x8 a1 = *(bf16x8*)&xs[m][32 + kg];
    int bn = lane & 15;
    f32x4 acc0 = {0.f,0.f,0.f,0.f}, acc1 = acc0, acc2 = acc0, acc3 = acc0;
    {
        bf16x8 b0 = *(bf16x8*)&Wb[bn][kg], b1 = *(bf16x8*)&Wb[bn][32 + kg];
        acc0 = __builtin_amdgcn_mfma_f32_16x16x32_bf16(a0, b0, acc0, 0, 0, 0);
        acc0 = __builtin_amdgcn_mfma_f32_16x16x32_bf16(a1, b1, acc0, 0, 0, 0);
    }
    {
        bf16x8 b0 = *(bf16x8*)&Wb[bn + 16][kg], b1 = *(bf16x8*)&Wb[bn + 16][32 + kg];
        acc1 = __builtin_amdgcn_mfma_f32_16x16x32_bf16(a0, b0, acc1, 0, 0, 0);
        acc1 = __builtin_amdgcn_mfma_f32_16x16x32_bf16(a1, b1, acc1, 0, 0, 0);
    }
    {
        bf16x8 b0 = *(bf16x8*)&Wb[bn + 32][kg], b1 = *(bf16x8*)&Wb[bn + 32][32 + kg];
        acc2 = __builtin_amdgcn_mfma_f32_16x16x32_bf16(a0, b0, acc2, 0, 0, 0);
        acc2 = __builtin_amdgcn_mfma_f32_16x16x32_bf16(a1, b1, acc2, 0, 0, 0);
    }
    {
        bf16x8 b0 = *(bf16x8*)&Wb[bn + 48][kg], b1 = *(bf16x8*)&Wb[bn + 48][32 + kg];
        acc3 = __builtin_amdgcn_mfma_f32_16x16x32_bf16(a0, b0, acc3, 0, 0, 0);
        acc3 = __builtin_amdgcn_mfma_f32_16x16x32_bf16(a1, b1, acc3, 0, 0, 0);
    }
    // C/D layout: col = lane&15, row = (lane>>4)*4 + reg  [m89-verified]
    int rbase = blockIdx.x * 64 + wid * 16 + (lane >> 4) * 4;
    #pragma unroll
    for (int i = 0; i < 4; ++i) {
        int r = rbase + i;
        if (r < n) {
            float dv = rsqrtf((float)(cnt[r] + 1));
            long long ro = (long long)r * 64 + (lane & 15);
            yb[ro +  0] = f2bf(dv * acc0[i]);
            yb[ro + 16] = f2bf(dv * acc1[i]);
            yb[ro + 32] = f2bf(dv * acc2[i]);
            yb[ro + 48] = f2bf(dv * acc3[i]);
        }
    }
}

// FUSED sort+gather: one 1024-thread block per bucket. LDS counting sort by
// dst&255 (sbuf never leaves LDS); then each 16-lane group gathers one dest's
// src list (broadcast ds_read) and writes out directly.
__global__ __launch_bounds__(1024) void k_aggr(const unsigned int* __restrict__ ebuf,
                                               const int* __restrict__ gcur,
                                               const int* __restrict__ cnt,
                                               const unsigned short* __restrict__ yb,
                                               const float* __restrict__ bias,
                                               float* __restrict__ out, int n) {
    __shared__ int h[256], hstart[256], hc[256], wsum[4];
    __shared__ int sbuf[CAP];                  // 20 KB, LDS-only
    int b = blockIdx.x, t = threadIdx.x;
    int s0 = b * CAP;
    int count = min(gcur[b] - s0, CAP);

    if (t < 256) h[t] = 0;
    __syncthreads();
    unsigned rec[5];
    #pragma unroll
    for (int k = 0; k < 5; ++k) {              // coalesced load + LDS hist
        int i = t + k * 1024;
        if (i < count) {
            unsigned p = ebuf[s0 + i];
            rec[k] = p;
            atomicAdd(&h[p >> 24], 1);
        }
    }
    __syncthreads();
    if (t < 256) {                             // wave-shfl inclusive scan
        int v = h[t];
        int lane = t & 63, wid = t >> 6;
        int incl = v;
        #pragma unroll
        for (int off = 1; off < 64; off <<= 1) {
            int u = __shfl_up(incl, off);
            if (lane >= off) incl += u;
        }
        hstart[t] = incl;                      // temp: inclusive
        if (lane == 63) wsum[wid] = incl;
    }
    __syncthreads();
    if (t < 256) {
        int wid = t >> 6;
        int add = 0;
        for (int w = 0; w < wid; ++w) add += wsum[w];
        int ex = hstart[t] - h[t] + add;       // exclusive prefix
        hstart[t] = ex;
        hc[t] = ex;
    }
    __syncthreads();
    #pragma unroll
    for (int k = 0; k < 5; ++k) {              // counting-sort scatter (LDS)
        int i = t + k * 1024;
        if (i < count) {
            unsigned p = rec[k];
            int r = atomicAdd(&hc[p >> 24], 1);
            sbuf[r] = (int)(p & 0x1FFFFu);
        }
    }
    __syncthreads();

    // Gather: 16 waves x 4 groups = 64 dest-slots; 4 rounds cover 256 dests.
    int lane = t & 63, w = t >> 6;
    int g = lane >> 4, q = lane & 15;
    #pragma unroll
    for (int r = 0; r < 4; ++r) {
        int cl = r * 64 + w * 4 + g;
        int c = b * 256 + cl;
        if (c >= n) continue;                  // no barriers below: safe
        int start = hstart[cl], len = h[cl];
        float a0 = 0.f, a1 = 0.f, a2 = 0.f, a3 = 0.f;
        if (len > 0) {
            int sc = sbuf[start];              // prefetched src
            for (int i = 0; i < len; ++i) {
                int sn = (i + 1 < len) ? sbuf[start + i + 1] : 0;
                float2 v = *(const float2*)(yb + (long long)sc * 64 + (q << 2));
                unsigned u0 = __float_as_uint(v.x), u1 = __float_as_uint(v.y);
                a0 += bflo(u0); a1 += bfhi(u0);
                a2 += bflo(u1); a3 += bfhi(u1);
                sc = sn;
            }
        }
        {   // self loop
            float2 v = *(const float2*)(yb + (long long)c * 64 + (q << 2));
            unsigned u0 = __float_as_uint(v.x), u1 = __float_as_uint(v.y);
            a0 += bflo(u0); a1 += bfhi(u0);
            a2 += bflo(u1); a3 += bfhi(u1);
        }
        float dc = rsqrtf((float)(cnt[c] + 1));
        float4 bv = *(const float4*)(bias + (q << 2));
        *(float4*)(out + (long long)c * 64 + (q << 2)) =
            make_float4(dc * a0 + bv.x, dc * a1 + bv.y,
                        dc * a2 + bv.z, dc * a3 + bv.w);
    }
}

extern "C" void kernel_launch(void* const* d_in, const int* in_sizes, int n_in,
                              void* d_out, int out_size, void* d_ws, size_t ws_size,
                              hipStream_t stream) {
    const float* x    = (const float*)d_in[0];
    const int*   ei   = (const int*)d_in[1];
    // d_in[2] = x0 (unused: use_init=False)
    const float* W    = (const float*)d_in[3];
    const float* bias = (const float*)d_in[4];
    float* out = (float*)d_out;

    int n = in_sizes[0] / 64;
    int E = in_sizes[1] / 2;
    const int* row = ei;        // source
    const int* col = ei + E;    // target

    int NB = (n + 255) / 256;   // 391 (<= NBMAX)

    char* ws = (char*)d_ws;
    size_t off = 0;
    auto alloc = [&](size_t bytes) { char* p = ws + off; off += (bytes + 15) & ~size_t(15); return p; };
    int*            cnt  = (int*)  alloc((size_t)n * 4);
    int*            gcur = (int*)  alloc((size_t)NB * 4);
    unsigned short* yb   = (unsigned short*)alloc((size_t)n * 64 * 2);
    unsigned int*   ebuf = (unsigned int*)alloc((size_t)NB * CAP * 4);

    int nbE = (E + 4095) / 4096;

    hipMemsetAsync(cnt, 0, (size_t)n * 4, stream);
    k_deg <<<(E / 4 + 255) / 256, 256, 0, stream>>>(col, cnt, gcur, E, NB);
    k_bin <<<nbE, 256, 0, stream>>>(row, col, gcur, ebuf, E);
    k_gemm<<<(n + 63) / 64, 256, 0, stream>>>(x, W, cnt, yb, n);
    k_aggr<<<NB, 1024, 0, stream>>>(ebuf, gcur, cnt, yb, bias, out, n);
}

// Round 8
// 178.945 us; speedup vs baseline: 1.3219x; 1.3219x over previous
//
#include <hip/hip_runtime.h>

// GCN layer: out = Ahat @ x @ W^T + bias, Ahat = D^-1/2 (A + I) D^-1/2
// Pipeline: fixed-capacity bucket binning (dst>>8, LDS counting sort,
// contiguous run writes) -> per-bucket LDS histogram => dinv (no global
// atomics anywhere) -> y' = dinv*(x@W^T) via bf16 MFMA -> FUSED per-bucket
// kernel: LDS counting-sort by dst&255 + per-dest gather + epilogue.

#define NBMAX 400
#define CAP   5120   // bucket capacity: mean 4096 + 16 sigma (sigma ~ 64)

typedef short bf16x8 __attribute__((ext_vector_type(8)));
typedef float f32x4  __attribute__((ext_vector_type(4)));

__device__ inline float bflo(unsigned u) { return __uint_as_float(u << 16); }
__device__ inline float bfhi(unsigned u) { return __uint_as_float(u & 0xFFFF0000u); }
__device__ inline unsigned short f2bf(float f) {           // round-nearest-even
    unsigned u = __float_as_uint(f);
    u += 0x7FFFu + ((u >> 16) & 1u);
    return (unsigned short)(u >> 16);
}

__global__ void k_initcur(int* __restrict__ gcur, int NB) {
    int b = threadIdx.x;
    if (b < NB) gcur[b] = b * CAP;
}

// Chunk-local LDS counting sort by bucket (dst>>8); contiguous run copy-out of
// packed (src | (dst&255)<<24) records into fixed-stride bucket regions.
__global__ __launch_bounds__(256) void k_bin(const int* __restrict__ row,
                                             const int* __restrict__ col,
                                             int* __restrict__ gcur,
                                             unsigned int* __restrict__ ebuf, int E) {
    __shared__ unsigned int   sorted4[4096];   // 16 KB packed records
    __shared__ unsigned short sbkt[4096];      //  8 KB bucket id per slot
    __shared__ int h[NBMAX], hstart[NBMAX], hcur[NBMAX], gof[NBMAX];
    int t = threadIdx.x;
    int base = blockIdx.x * 4096;
    int total = min(4096, E - base);

    int rr[16], cc[16];
    #pragma unroll
    for (int i = 0; i < 4; ++i) {
        int e0 = (t + i * 256) * 4;
        if (e0 + 3 < total) {
            int4 r4 = *(const int4*)(row + base + e0);
            int4 c4 = *(const int4*)(col + base + e0);
            rr[i*4+0]=r4.x; rr[i*4+1]=r4.y; rr[i*4+2]=r4.z; rr[i*4+3]=r4.w;
            cc[i*4+0]=c4.x; cc[i*4+1]=c4.y; cc[i*4+2]=c4.z; cc[i*4+3]=c4.w;
        } else {
            #pragma unroll
            for (int j = 0; j < 4; ++j) {
                int e = e0 + j;
                if (e < total) { rr[i*4+j] = row[base+e]; cc[i*4+j] = col[base+e]; }
                else cc[i*4+j] = -1;
            }
        }
    }
    for (int b = t; b < NBMAX; b += 256) h[b] = 0;
    __syncthreads();
    #pragma unroll
    for (int i = 0; i < 16; ++i)
        if (cc[i] >= 0) atomicAdd(&h[cc[i] >> 8], 1);
    __syncthreads();
    if (t < 64) {                              // wave-0 scan of h
        int lo = t * 7;
        int loc[7]; int s = 0;
        #pragma unroll
        for (int i = 0; i < 7; ++i) {
            loc[i] = s;
            int idx = lo + i;
            s += (idx < NBMAX) ? h[idx] : 0;
        }
        int incl = s;
        for (int off = 1; off < 64; off <<= 1) {
            int v = __shfl_up(incl, off);
            if (t >= off) incl += v;
        }
        int ex = incl - s;
        #pragma unroll
        for (int i = 0; i < 7; ++i) {
            int idx = lo + i;
            if (idx < NBMAX) hstart[idx] = ex + loc[i];
        }
    }
    __syncthreads();
    for (int b = t; b < NBMAX; b += 256) hcur[b] = hstart[b];
    __syncthreads();
    #pragma unroll
    for (int i = 0; i < 16; ++i) {
        if (cc[i] >= 0) {
            int b = cc[i] >> 8;
            int rank = atomicAdd(&hcur[b], 1);
            sorted4[rank] = (unsigned)rr[i] | ((unsigned)(cc[i] & 255) << 24);
            sbkt[rank] = (unsigned short)b;
        }
    }
    for (int b = t; b < NBMAX; b += 256) {
        int m = h[b];
        gof[b] = m ? atomicAdd(&gcur[b], m) : 0;
    }
    __syncthreads();
    for (int i = t; i < total; i += 256) {     // contiguous per-bucket runs
        int b = sbkt[i];
        ebuf[gof[b] + (i - hstart[b])] = sorted4[i];
    }
}

// Per-bucket degree histogram -> dinv. Coalesced 16 KB read, LDS atomics only.
__global__ __launch_bounds__(256) void k_cnt(const unsigned int* __restrict__ ebuf,
                                             const int* __restrict__ gcur,
                                             float* __restrict__ dinv, int n) {
    __shared__ int h[256];
    int b = blockIdx.x, t = threadIdx.x;
    int s0 = b * CAP;
    int count = min(gcur[b] - s0, CAP);
    h[t] = 0;
    __syncthreads();
    for (int i = t; i < count; i += 256) atomicAdd(&h[ebuf[s0 + i] >> 24], 1);
    __syncthreads();
    int c = b * 256 + t;
    if (c < n) dinv[c] = rsqrtf((float)(h[t] + 1));
}

// y' = dinv * (x @ W^T) via bf16 MFMA 16x16x32; 64 rows per block.
// LDS rows padded to 72 bf16 (144 B -> 2-way max bank aliasing).
__global__ __launch_bounds__(256) void k_gemm(const float* __restrict__ x,
                                              const float* __restrict__ W,
                                              const float* __restrict__ dinv,
                                              unsigned short* __restrict__ yb, int n) {
    __shared__ __align__(16) unsigned short xs[64][72];
    __shared__ __align__(16) unsigned short Wb[64][72];
    int t = threadIdx.x;
    long long total = (long long)n * 64;
    long long xbase = (long long)blockIdx.x * 4096;
    #pragma unroll
    for (int i = 0; i < 4; ++i) {
        int idx = t + i * 256;                 // float4 index 0..1023
        int r = idx >> 4, c4 = (idx & 15) << 2;
        long long g = xbase + (long long)idx * 4;
        float4 v;
        if (g + 3 < total) v = *(const float4*)(x + g);
        else {
            v.x = (g + 0 < total) ? x[g + 0] : 0.f;
            v.y = (g + 1 < total) ? x[g + 1] : 0.f;
            v.z = (g + 2 < total) ? x[g + 2] : 0.f;
            v.w = (g + 3 < total) ? x[g + 3] : 0.f;
        }
        ushort4 o; o.x = f2bf(v.x); o.y = f2bf(v.y); o.z = f2bf(v.z); o.w = f2bf(v.w);
        *(ushort4*)&xs[r][c4] = o;
        float4 wv = *(const float4*)(W + idx * 4);     // W: 4096 floats
        ushort4 wo; wo.x = f2bf(wv.x); wo.y = f2bf(wv.y); wo.z = f2bf(wv.z); wo.w = f2bf(wv.w);
        *(ushort4*)&Wb[r][c4] = wo;
    }
    __syncthreads();
    int lane = t & 63, wid = t >> 6;
    int m  = wid * 16 + (lane & 15);
    int kg = (lane >> 4) * 8;
    bf16x8 a0 = *(bf16x8*)&xs[m][kg];
    bf16x8 a1 = *(bf16x8*)&xs[m][32 + kg];
    int bn = lane & 15;
    f32x4 acc0 = {0.f,0.f,0.f,0.f}, acc1 = acc0, acc2 = acc0, acc3 = acc0;
    {
        bf16x8 b0 = *(bf16x8*)&Wb[bn][kg], b1 = *(bf16x8*)&Wb[bn][32 + kg];
        acc0 = __builtin_amdgcn_mfma_f32_16x16x32_bf16(a0, b0, acc0, 0, 0, 0);
        acc0 = __builtin_amdgcn_mfma_f32_16x16x32_bf16(a1, b1, acc0, 0, 0, 0);
    }
    {
        bf16x8 b0 = *(bf16x8*)&Wb[bn + 16][kg], b1 = *(bf16x8*)&Wb[bn + 16][32 + kg];
        acc1 = __builtin_amdgcn_mfma_f32_16x16x32_bf16(a0, b0, acc1, 0, 0, 0);
        acc1 = __builtin_amdgcn_mfma_f32_16x16x32_bf16(a1, b1, acc1, 0, 0, 0);
    }
    {
        bf16x8 b0 = *(bf16x8*)&Wb[bn + 32][kg], b1 = *(bf16x8*)&Wb[bn + 32][32 + kg];
        acc2 = __builtin_amdgcn_mfma_f32_16x16x32_bf16(a0, b0, acc2, 0, 0, 0);
        acc2 = __builtin_amdgcn_mfma_f32_16x16x32_bf16(a1, b1, acc2, 0, 0, 0);
    }
    {
        bf16x8 b0 = *(bf16x8*)&Wb[bn + 48][kg], b1 = *(bf16x8*)&Wb[bn + 48][32 + kg];
        acc3 = __builtin_amdgcn_mfma_f32_16x16x32_bf16(a0, b0, acc3, 0, 0, 0);
        acc3 = __builtin_amdgcn_mfma_f32_16x16x32_bf16(a1, b1, acc3, 0, 0, 0);
    }
    // C/D layout: col = lane&15, row = (lane>>4)*4 + reg  [m89-verified]
    int rbase = blockIdx.x * 64 + wid * 16 + (lane >> 4) * 4;
    #pragma unroll
    for (int i = 0; i < 4; ++i) {
        int r = rbase + i;
        if (r < n) {
            float dv = dinv[r];
            long long ro = (long long)r * 64 + (lane & 15);
            yb[ro +  0] = f2bf(dv * acc0[i]);
            yb[ro + 16] = f2bf(dv * acc1[i]);
            yb[ro + 32] = f2bf(dv * acc2[i]);
            yb[ro + 48] = f2bf(dv * acc3[i]);
        }
    }
}

// FUSED sort+gather: one 1024-thread block per bucket. LDS counting sort by
// dst&255 (sbuf never leaves LDS); then each 16-lane group gathers one dest's
// src list (broadcast ds_read) and writes out directly.
__global__ __launch_bounds__(1024) void k_aggr(const unsigned int* __restrict__ ebuf,
                                               const int* __restrict__ gcur,
                                               const float* __restrict__ dinv,
                                               const unsigned short* __restrict__ yb,
                                               const float* __restrict__ bias,
                                               float* __restrict__ out, int n) {
    __shared__ int h[256], hstart[256], hc[256], wsum[4];
    __shared__ int sbuf[CAP];                  // 20 KB, LDS-only
    int b = blockIdx.x, t = threadIdx.x;
    int s0 = b * CAP;
    int count = min(gcur[b] - s0, CAP);

    if (t < 256) h[t] = 0;
    __syncthreads();
    unsigned rec[5];
    #pragma unroll
    for (int k = 0; k < 5; ++k) {              // coalesced load + LDS hist
        int i = t + k * 1024;
        if (i < count) {
            unsigned p = ebuf[s0 + i];
            rec[k] = p;
            atomicAdd(&h[p >> 24], 1);
        }
    }
    __syncthreads();
    if (t < 256) {                             // wave-shfl inclusive scan
        int v = h[t];
        int lane = t & 63, wid = t >> 6;
        int incl = v;
        #pragma unroll
        for (int off = 1; off < 64; off <<= 1) {
            int u = __shfl_up(incl, off);
            if (lane >= off) incl += u;
        }
        hstart[t] = incl;                      // temp: inclusive
        if (lane == 63) wsum[wid] = incl;
    }
    __syncthreads();
    if (t < 256) {
        int wid = t >> 6;
        int add = 0;
        for (int w = 0; w < wid; ++w) add += wsum[w];
        int ex = hstart[t] - h[t] + add;       // exclusive prefix
        hstart[t] = ex;
        hc[t] = ex;
    }
    __syncthreads();
    #pragma unroll
    for (int k = 0; k < 5; ++k) {              // counting-sort scatter (LDS)
        int i = t + k * 1024;
        if (i < count) {
            unsigned p = rec[k];
            int r = atomicAdd(&hc[p >> 24], 1);
            sbuf[r] = (int)(p & 0x1FFFFu);
        }
    }
    __syncthreads();

    // Gather: 16 waves x 4 groups = 64 dest-slots; 4 rounds cover 256 dests.
    int lane = t & 63, w = t >> 6;
    int g = lane >> 4, q = lane & 15;
    #pragma unroll
    for (int r = 0; r < 4; ++r) {
        int cl = r * 64 + w * 4 + g;
        int c = b * 256 + cl;
        if (c >= n) continue;                  // no barriers below: safe
        int start = hstart[cl], len = h[cl];
        float a0 = 0.f, a1 = 0.f, a2 = 0.f, a3 = 0.f;
        if (len > 0) {
            int sc = sbuf[start];              // prefetched src
            for (int i = 0; i < len; ++i) {
                int sn = (i + 1 < len) ? sbuf[start + i + 1] : 0;
                float2 v = *(const float2*)(yb + (long long)sc * 64 + (q << 2));
                unsigned u0 = __float_as_uint(v.x), u1 = __float_as_uint(v.y);
                a0 += bflo(u0); a1 += bfhi(u0);
                a2 += bflo(u1); a3 += bfhi(u1);
                sc = sn;
            }
        }
        {   // self loop
            float2 v = *(const float2*)(yb + (long long)c * 64 + (q << 2));
            unsigned u0 = __float_as_uint(v.x), u1 = __float_as_uint(v.y);
            a0 += bflo(u0); a1 += bfhi(u0);
            a2 += bflo(u1); a3 += bfhi(u1);
        }
        float dc = dinv[c];
        float4 bv = *(const float4*)(bias + (q << 2));
        *(float4*)(out + (long long)c * 64 + (q << 2)) =
            make_float4(dc * a0 + bv.x, dc * a1 + bv.y,
                        dc * a2 + bv.z, dc * a3 + bv.w);
    }
}

extern "C" void kernel_launch(void* const* d_in, const int* in_sizes, int n_in,
                              void* d_out, int out_size, void* d_ws, size_t ws_size,
                              hipStream_t stream) {
    const float* x    = (const float*)d_in[0];
    const int*   ei   = (const int*)d_in[1];
    // d_in[2] = x0 (unused: use_init=False)
    const float* W    = (const float*)d_in[3];
    const float* bias = (const float*)d_in[4];
    float* out = (float*)d_out;

    int n = in_sizes[0] / 64;
    int E = in_sizes[1] / 2;
    const int* row = ei;        // source
    const int* col = ei + E;    // target

    int NB = (n + 255) / 256;   // 391 (<= NBMAX, <= 512)

    char* ws = (char*)d_ws;
    size_t off = 0;
    auto alloc = [&](size_t bytes) { char* p = ws + off; off += (bytes + 15) & ~size_t(15); return p; };
    int*            gcur = (int*)  alloc((size_t)NB * 4);
    float*          dinv = (float*)alloc((size_t)n * 4);
    unsigned short* yb   = (unsigned short*)alloc((size_t)n * 64 * 2);
    unsigned int*   ebuf = (unsigned int*)alloc((size_t)NB * CAP * 4);

    int nbE = (E + 4095) / 4096;

    k_initcur<<<1, 512, 0, stream>>>(gcur, NB);
    k_bin <<<nbE, 256, 0, stream>>>(row, col, gcur, ebuf, E);
    k_cnt <<<NB, 256, 0, stream>>>(ebuf, gcur, dinv, n);
    k_gemm<<<(n + 63) / 64, 256, 0, stream>>>(x, W, dinv, yb, n);
    k_aggr<<<NB, 1024, 0, stream>>>(ebuf, gcur, dinv, yb, bias, out, n);
}